// Round 4
// baseline (165.061 us; speedup 1.0000x reference)
//
#include <hip/hip_runtime.h>
#include <math.h>

// Fused QWZ deformation + HS-distance kernel, v6: wide-load variant.
// Evidence: v2/v3/v5 (very different scheduling structures) all run 52-54us at
// a constant 2.85-2.95 TB/s; no pipe saturated. Theory: per-CU outstanding
// *load-instruction* slots cap MLP; all prior variants load 5 narrow insts per
// site (avg 5.6 B/lane/inst). v6 changes ONE variable: all global loads become
// 16B dwordx4. Each loader thread owns 4 consecutive sites; the angle n-1
// shift comes from the neighbor lane's .w via __shfl_up (scalar fallback at
// group/wave/wrap boundaries).
#define TILE  32
#define HALO  33                 // TILE + 1
#define NHALO (HALO * HALO)      // 1089
#define NGRP  9                  // 4-site groups per halo row (covers 36 cols)
#define NASSIGN (HALO * NGRP)    // 297 loader threads per tile
#define TPB   512

__device__ __forceinline__ float4 deform1(float th, float ph, float ps,
                                          float2 r, float2 im, bool origin) {
    float st, ct, sp, cp, sq, cq;
    __sincosf(th, &st, &ct);
    __sincosf(ph, &sp, &cp);
    __sincosf(ps, &sq, &cq);
    float a = ct * cp;   // su_re diag
    float b = st * cq;   // su_re off-diag
    float c = ct * sp;   // su_im diag
    float d = st * sq;   // su_im off-diag
    // d_re = su_re@s_re - su_im@s_im ; d_im = su_re@s_im + su_im@s_re
    float4 d4;
    d4.x = a * r.x - b * r.y - c * im.x + d * im.y;
    d4.y = b * r.x + a * r.y + d * im.x + c * im.y;
    d4.z = a * im.x - b * im.y + c * r.x - d * r.y;
    d4.w = b * im.x + a * im.y - d * r.x - c * r.y;
    if (origin) d4 = make_float4(r.x, r.y, im.x, im.y);  // site 0 undeformed
    return d4;
}

__device__ __forceinline__ float hsdist(float4 A, float4 B) {
    float rr = A.x * B.x + A.y * B.y + A.z * B.z + A.w * B.w;
    float ri = A.x * B.z + A.y * B.w - A.z * B.x - A.w * B.y;
    return sqrtf(fabsf(1.0f - rr * rr - ri * ri));
}

__global__ __launch_bounds__(TPB, 4) void qwz_deform_dirichlet_kernel(
    const float* __restrict__ theta,
    const float* __restrict__ phi,
    const float* __restrict__ psi,
    const float2* __restrict__ sre,   // state_re as [N] float2
    const float2* __restrict__ sim,   // state_im as [N] float2
    float* __restrict__ out,          // [3, mesh, mesh]
    int mesh)
{
    const int N = mesh * mesh;
    __shared__ float4 tile[NHALO];

    const int tid  = threadIdx.x;
    const int lane = tid & 63;
    const int bi = blockIdx.y * TILE;
    const int bj = blockIdx.x * TILE;

    // ---- Phase 1: wide-load + deform (threads 0..296) ----
    if (tid < NASSIGN) {
        const int r = tid / NGRP;          // halo row 0..32
        const int g = tid - r * NGRP;      // group 0..8 (cols 4g..4g+3)
        int gi = bi + r; if (gi >= mesh) gi -= mesh;
        const bool colwrap = (bj + 4 * g >= mesh);   // whole group wraps (mesh%4==0)
        int gcol = bj + 4 * g; if (colwrap) gcol -= mesh;
        const int n0 = gi * mesh + gcol;   // n0 % 4 == 0 -> 16B aligned

        // angles for sites n0..n0+3 come from indices n0-1..n0+2;
        // load the aligned quad [n0..n0+3]; the n0-1 value comes from lane-1.
        float4 thq, phq, psq;
        if (n0 + 4 < N) {
            thq = *(const float4*)(theta + n0);
            phq = *(const float4*)(phi   + n0);
            psq = *(const float4*)(psi   + n0);
        } else {                           // theta has N-1 elems; last quad scalar
            thq = make_float4(theta[n0], theta[n0 + 1], theta[n0 + 2], 0.f);
            phq = make_float4(phi[n0],   phi[n0 + 1],   phi[n0 + 2],   0.f);
            psq = make_float4(psi[n0],   psi[n0 + 1],   psi[n0 + 2],   0.f);
        }
        const float4 s01 = *(const float4*)((const float*)sre + 2 * n0);
        const float4 s23 = *(const float4*)((const float*)sre + 2 * n0 + 4);
        const float4 i01 = *(const float4*)((const float*)sim + 2 * n0);
        const float4 i23 = *(const float4*)((const float*)sim + 2 * n0 + 4);

        // n0-1 angles: neighbor lane's .w (same row, group g-1, n0'=n0-4),
        // scalar fallback where that lane is wrong/unreachable.
        float thm = __shfl_up(thq.w, 1, 64);
        float phm = __shfl_up(phq.w, 1, 64);
        float psm = __shfl_up(psq.w, 1, 64);
        if (lane == 0 || g == 0 || colwrap) {
            int am = (n0 > 0) ? n0 - 1 : 0;   // junk only for origin site (unused)
            thm = theta[am]; phm = phi[am]; psm = psi[am];
        }

        const int lbase = r * HALO + 4 * g;
        float4 d0 = deform1(thm, phm, psm,
                            make_float2(s01.x, s01.y), make_float2(i01.x, i01.y),
                            n0 == 0);
        tile[lbase] = d0;                          // 4g <= 32 always
        float4 d1 = deform1(thq.x, phq.x, psq.x,
                            make_float2(s01.z, s01.w), make_float2(i01.z, i01.w),
                            false);
        if (4 * g + 1 < HALO) tile[lbase + 1] = d1;
        float4 d2 = deform1(thq.y, phq.y, psq.y,
                            make_float2(s23.x, s23.y), make_float2(i23.x, i23.y),
                            false);
        if (4 * g + 2 < HALO) tile[lbase + 2] = d2;
        float4 d3 = deform1(thq.z, phq.z, psq.z,
                            make_float2(s23.z, s23.w), make_float2(i23.z, i23.w),
                            false);
        if (4 * g + 3 < HALO) tile[lbase + 3] = d3;
    }
    __syncthreads();

    // ---- Phase 2: 2 output rows per thread (identical to v5) ----
    const int trow = (tid >> 5) << 1;   // 0,2,...,30
    const int tcol = tid & 31;

    float4 A = tile[trow * HALO + tcol];
    float4 V = tile[trow * HALO + tcol + 1];
    int site = (bi + trow) * mesh + (bj + tcol);

#pragma unroll
    for (int k = 0; k < 2; ++k) {
        float4 H = tile[(trow + k + 1) * HALO + tcol];
        float4 D = tile[(trow + k + 1) * HALO + tcol + 1];

        float v = hsdist(A, V);   // (i,j)-(i,j+1)
        float h = hsdist(A, H);   // (i,j)-(i+1,j)
        float d = hsdist(A, D);   // (i,j)-(i+1,j+1)

        __builtin_nontemporal_store(v, out + site);
        __builtin_nontemporal_store(h, out + N + site);
        __builtin_nontemporal_store(d, out + 2 * N + site);

        A = H; V = D;
        site += mesh;
    }
}

extern "C" void kernel_launch(void* const* d_in, const int* in_sizes, int n_in,
                              void* d_out, int out_size, void* d_ws, size_t ws_size,
                              hipStream_t stream) {
    const float* theta = (const float*)d_in[0];
    const float* phi   = (const float*)d_in[1];
    const float* psi   = (const float*)d_in[2];
    const float2* sre  = (const float2*)d_in[3];
    const float2* sim  = (const float2*)d_in[4];
    float* out = (float*)d_out;

    int N = in_sizes[0] + 1;                       // theta has N-1 elements
    int mesh = (int)(sqrt((double)N) + 0.5);       // 2048

    dim3 grid(mesh / TILE, mesh / TILE);           // (64, 64)
    dim3 block(TPB);
    qwz_deform_dirichlet_kernel<<<grid, block, 0, stream>>>(
        theta, phi, psi, sre, sim, out, mesh);
}